// Round 13
// baseline (126.737 us; speedup 1.0000x reference)
//
#include <hip/hip_runtime.h>
#include <hip/hip_fp16.h>

#define F_OUT 37
#define BSHIFT 7
#define BSIZE 128          // nodes per bucket
#define CAP 3072           // edge capacity per bucket region (mean 2048, max ~2300)
#define STAGE_CAP 6144     // max edges staged per bucketA block (24 KB LDS)
#define XS_STRIDE 68       // 64 + 4 pad: breaks bank aliasing, keeps 16B align

// ---------- fp16 pack/unpack helpers ----------
__device__ __forceinline__ short4 pack4(float a, float b, float c, float d) {
    union { __half2 h2[2]; short4 s; } u;
    u.h2[0] = __floats2half2_rn(a, b);
    u.h2[1] = __floats2half2_rn(c, d);
    return u.s;
}
__device__ __forceinline__ float4 unpack4(short4 v) {
    union { short4 s; __half2 h2[2]; } u;
    u.s = v;
    float2 lo = __half22float2(u.h2[0]);
    float2 hi = __half22float2(u.h2[1]);
    return make_float4(lo.x, lo.y, hi.x, hi.y);
}
// nt store of a short4 via integer punning (builtin requires int/float/ptr types)
__device__ __forceinline__ void nt_store_s4(short4 v, short4* p) {
    union { short4 s; unsigned long long u; } cv;
    cv.s = v;
    __builtin_nontemporal_store(cv.u, (unsigned long long*)p);
}

// ================= bucket-sort CSR build (fixed regions, no scan) =================

__global__ __launch_bounds__(256) void bucketA(const int* __restrict__ src,
                                               const int* __restrict__ dst,
                                               int E, int C, int nb,
                                               int* __restrict__ gcur,
                                               unsigned* __restrict__ bedge) {
    __shared__ unsigned stage[STAGE_CAP];
    __shared__ int lcnt[400];
    __shared__ int lbase[400];
    int t = threadIdx.x;
    int e0 = blockIdx.x * C;
    int cnt = E - e0; if (cnt > C) cnt = C; if (cnt <= 0) return;

    for (int i = t; i < nb; i += 256) lcnt[i] = 0;
    __syncthreads();
    for (int i = t; i < cnt; i += 256) {
        int s = src[e0 + i], d = dst[e0 + i];
        int b = d >> BSHIFT;
        atomicAdd(&lcnt[b], 1);
        stage[i] = ((unsigned)b << 23) | ((unsigned)(d & (BSIZE - 1)) << 16) | (unsigned)s;
    }
    __syncthreads();
    for (int i = t; i < nb; i += 256)
        lbase[i] = lcnt[i] ? atomicAdd(&gcur[i * 16], lcnt[i]) : 0;
    __syncthreads();
    for (int i = t; i < nb; i += 256) lcnt[i] = 0;   // reuse as cursor
    __syncthreads();
    for (int i = t; i < cnt; i += 256) {
        unsigned w = stage[i];
        int b = w >> 23;
        int pos = b * CAP + lbase[b] + atomicAdd(&lcnt[b], 1);
        bedge[pos] = w & 0x7FFFFFu;                  // (dloc<<16)|src
    }
}

__global__ __launch_bounds__(256) void bucketB(const unsigned* __restrict__ bedge,
                                               const int* __restrict__ gcur,
                                               int n,
                                               int* __restrict__ rowbeg,
                                               int* __restrict__ rowend,
                                               int* __restrict__ srcIdx,
                                               float* __restrict__ dinv) {
    __shared__ int hcnt[BSIZE], hoff[BSIZE], hcur[BSIZE], tmp[BSIZE];
    int b = blockIdx.x;
    int t = threadIdx.x;
    int cntb = gcur[b * 16];
    int base = b * CAP;
    const unsigned* ed = bedge + (size_t)base;

    if (t < BSIZE) { hcnt[t] = 0; hcur[t] = 0; }
    __syncthreads();
    for (int i = t; i < cntb; i += 256) atomicAdd(&hcnt[ed[i] >> 16], 1);
    __syncthreads();
    if (t < BSIZE) tmp[t] = hcnt[t];
    __syncthreads();
    for (int o = 1; o < BSIZE; o <<= 1) {
        int a = (t < BSIZE && t >= o) ? tmp[t - o] : 0;
        __syncthreads();
        if (t < BSIZE) tmp[t] += a;
        __syncthreads();
    }
    if (t < BSIZE) hoff[t] = tmp[t] - hcnt[t];
    __syncthreads();
    int node = b * BSIZE + t;
    if (t < BSIZE && node < n) {
        rowbeg[node] = base + hoff[t];
        rowend[node] = base + hoff[t] + hcnt[t];
        dinv[node] = rsqrtf(1.0f + (float)hcnt[t]);   // +1 self-loop
    }
    for (int i = t; i < cntb; i += 256) {
        unsigned w = ed[i];
        int dloc = w >> 16;
        int pos = base + hoff[dloc] + atomicAdd(&hcur[dloc], 1);
        srcIdx[pos] = (int)(w & 0xFFFFu);
    }
}

// ================= dense layers: 64x64 block tile, 4x4 per thread =================

#define MICRO_STEP(XI, ACC)                                                    \
    do {                                                                       \
        ACC[0] += XI.x * w0.x; ACC[1] += XI.x * w0.y;                          \
        ACC[2] += XI.x * w0.z; ACC[3] += XI.x * w0.w;                          \
        ACC[0] += XI.y * w1.x; ACC[1] += XI.y * w1.y;                          \
        ACC[2] += XI.y * w1.z; ACC[3] += XI.y * w1.w;                          \
        ACC[0] += XI.z * w2.x; ACC[1] += XI.z * w2.y;                          \
        ACC[2] += XI.z * w2.z; ACC[3] += XI.z * w2.w;                          \
        ACC[0] += XI.w * w3.x; ACC[1] += XI.w * w3.y;                          \
        ACC[2] += XI.w * w3.z; ACC[3] += XI.w * w3.w;                          \
    } while (0)

// slice tables (fp16): hv0[row][0..31], hv1[row][32..63]; value = dinv*x@W1
__global__ __launch_bounds__(256, 4) void gemm64(const float* __restrict__ x,
                                                 const float* __restrict__ W,
                                                 const float* __restrict__ dinv,
                                                 short4* __restrict__ hv0,
                                                 short4* __restrict__ hv1, int n) {
    __shared__ float Xs[64 * XS_STRIDE];
    __shared__ float Ws[64 * 64];
    int t = threadIdx.x;
    const float4* W4 = (const float4*)W;
#pragma unroll
    for (int i = 0; i < 4; ++i)
        ((float4*)Ws)[t + i * 256] = W4[t + i * 256];
    int row0 = blockIdx.x * 64;
#pragma unroll
    for (int i = 0; i < 4; ++i) {
        int idx = i * 256 + t;            // 0..1023
        int r = idx >> 4, k4 = idx & 15;
        int grow = row0 + r;
        float4 v = (grow < n) ? ((const float4*)x)[(size_t)grow * 16 + k4]
                              : make_float4(0.f, 0.f, 0.f, 0.f);
        *(float4*)&Xs[r * XS_STRIDE + k4 * 4] = v;
    }
    __syncthreads();

    int tc = t & 15, tr = t >> 4;
    float a0[4] = {0.f, 0.f, 0.f, 0.f};
    float a1[4] = {0.f, 0.f, 0.f, 0.f};
    float a2[4] = {0.f, 0.f, 0.f, 0.f};
    float a3[4] = {0.f, 0.f, 0.f, 0.f};

#pragma unroll 2
    for (int k = 0; k < 64; k += 4) {
        float4 w0 = *(const float4*)&Ws[(k + 0) * 64 + 4 * tc];
        float4 w1 = *(const float4*)&Ws[(k + 1) * 64 + 4 * tc];
        float4 w2 = *(const float4*)&Ws[(k + 2) * 64 + 4 * tc];
        float4 w3 = *(const float4*)&Ws[(k + 3) * 64 + 4 * tc];
        float4 x0 = *(const float4*)&Xs[(4 * tr + 0) * XS_STRIDE + k];
        float4 x1 = *(const float4*)&Xs[(4 * tr + 1) * XS_STRIDE + k];
        float4 x2 = *(const float4*)&Xs[(4 * tr + 2) * XS_STRIDE + k];
        float4 x3 = *(const float4*)&Xs[(4 * tr + 3) * XS_STRIDE + k];
        MICRO_STEP(x0, a0);
        MICRO_STEP(x1, a1);
        MICRO_STEP(x2, a2);
        MICRO_STEP(x3, a3);
    }

    short4* tab = (tc < 8) ? hv0 : hv1;
    int lc = tc & 7;
#define STORE64(ACC, R)                                                        \
    do {                                                                       \
        int row = row0 + 4 * tr + (R);                                         \
        if (row < n) {                                                         \
            float dd = dinv[row];                                              \
            tab[(size_t)row * 8 + lc] =                                        \
                pack4(ACC[0] * dd, ACC[1] * dd, ACC[2] * dd, ACC[3] * dd);     \
        }                                                                      \
    } while (0)
    STORE64(a0, 0); STORE64(a1, 1); STORE64(a2, 2); STORE64(a3, 3);
#undef STORE64
}

// layer-2 GEMM: reads h1 slices, writes g32 (64B rows) + g8 (16B rows, 800KB)
__global__ __launch_bounds__(256, 4) void gemm37(const short4* __restrict__ h1v0,
                                                 const short4* __restrict__ h1v1,
                                                 const float* __restrict__ W,
                                                 short4* __restrict__ g32v,
                                                 short4* __restrict__ g8v, int n) {
    __shared__ float Xs[64 * XS_STRIDE];
    __shared__ float Ws[64 * 64];       // zero-padded cols 37..63
    int t = threadIdx.x;
    for (int i = t; i < 64 * 64; i += 256) {
        int k = i >> 6, c = i & 63;
        Ws[i] = (c < F_OUT) ? W[k * F_OUT + c] : 0.f;
    }
    int row0 = blockIdx.x * 64;
#pragma unroll
    for (int i = 0; i < 4; ++i) {
        int idx = i * 256 + t;
        int r = idx >> 4, k4 = idx & 15;
        int grow = row0 + r;
        float4 v = make_float4(0.f, 0.f, 0.f, 0.f);
        if (grow < n)
            v = unpack4((k4 < 8) ? h1v0[(size_t)grow * 8 + k4]
                                 : h1v1[(size_t)grow * 8 + (k4 - 8)]);
        *(float4*)&Xs[r * XS_STRIDE + k4 * 4] = v;
    }
    __syncthreads();

    int tc = t & 15, tr = t >> 4;
    float a0[4] = {0.f, 0.f, 0.f, 0.f};
    float a1[4] = {0.f, 0.f, 0.f, 0.f};
    float a2[4] = {0.f, 0.f, 0.f, 0.f};
    float a3[4] = {0.f, 0.f, 0.f, 0.f};

#pragma unroll 2
    for (int k = 0; k < 64; k += 4) {
        float4 w0 = *(const float4*)&Ws[(k + 0) * 64 + 4 * tc];
        float4 w1 = *(const float4*)&Ws[(k + 1) * 64 + 4 * tc];
        float4 w2 = *(const float4*)&Ws[(k + 2) * 64 + 4 * tc];
        float4 w3 = *(const float4*)&Ws[(k + 3) * 64 + 4 * tc];
        float4 x0 = *(const float4*)&Xs[(4 * tr + 0) * XS_STRIDE + k];
        float4 x1 = *(const float4*)&Xs[(4 * tr + 1) * XS_STRIDE + k];
        float4 x2 = *(const float4*)&Xs[(4 * tr + 2) * XS_STRIDE + k];
        float4 x3 = *(const float4*)&Xs[(4 * tr + 3) * XS_STRIDE + k];
        MICRO_STEP(x0, a0);
        MICRO_STEP(x1, a1);
        MICRO_STEP(x2, a2);
        MICRO_STEP(x3, a3);
    }

    if (tc < 10) {   // cols 0..39 live
#define STORE37(ACC, R)                                                        \
        do {                                                                   \
            int row = row0 + 4 * tr + (R);                                     \
            if (row < n) {                                                     \
                short4 pv = pack4(ACC[0], ACC[1], ACC[2], ACC[3]);             \
                if (tc < 8) g32v[(size_t)row * 8 + tc] = pv;                   \
                else        g8v[(size_t)row * 2 + (tc - 8)] = pv;              \
            }                                                                  \
        } while (0)
        STORE37(a0, 0); STORE37(a1, 1); STORE37(a2, 2); STORE37(a3, 3);
#undef STORE37
    }
}

// ================= gather aggregation (fp16 tables, fp32 accum) =================

#define ACCP4(A, B, C, D)                                                      \
    acc.x += (A.x + B.x) + (C.x + D.x);                                        \
    acc.y += (A.y + B.y) + (C.y + D.y);                                        \
    acc.z += (A.z + B.z) + (C.z + D.z);                                        \
    acc.w += (A.w + B.w) + (C.w + D.w);

// layer-1 slice aggregation: 8 lanes/node, 8B/lane = exactly one 64B line/edge.
// Launched once per slice (sequential) so the 3.2MB table is L2-resident.
// Output via nontemporal stores to avoid evicting the gather table.
__global__ void agg64s(const int* __restrict__ rowbeg,
                       const int* __restrict__ rowend,
                       const int* __restrict__ srcIdx,
                       const float* __restrict__ dinv,
                       const short4* __restrict__ tab,
                       const float* __restrict__ bias,
                       short4* __restrict__ outv, int n) {
    int t = blockIdx.x * blockDim.x + threadIdx.x;
    int d = t >> 3, sub = t & 7;
    if (d >= n) return;
    int gbase = threadIdx.x & 56;   // 8-lane group base within wave

    float4 acc = unpack4(tab[(size_t)d * 8 + sub]);   // self-loop term
    int beg = __builtin_nontemporal_load(&rowbeg[d]);
    int end = __builtin_nontemporal_load(&rowend[d]);
    int j = beg;
#define LDA8(Q) float4 va##Q = unpack4(tab[(size_t)__shfl(idxA, gbase + Q) * 8 + sub]);
#define LDB8(Q) float4 vb##Q = unpack4(tab[(size_t)__shfl(idxB, gbase + Q) * 8 + sub]);
    for (; j + 16 <= end; j += 16) {
        int idxA = __builtin_nontemporal_load(&srcIdx[j + sub]);
        int idxB = __builtin_nontemporal_load(&srcIdx[j + 8 + sub]);
        LDA8(0) LDA8(1) LDA8(2) LDA8(3) LDA8(4) LDA8(5) LDA8(6) LDA8(7)
        LDB8(0) LDB8(1) LDB8(2) LDB8(3) LDB8(4) LDB8(5) LDB8(6) LDB8(7)
        ACCP4(va0, va1, va2, va3) ACCP4(va4, va5, va6, va7)
        ACCP4(vb0, vb1, vb2, vb3) ACCP4(vb4, vb5, vb6, vb7)
    }
    if (j + 8 <= end) {
        int idxA = __builtin_nontemporal_load(&srcIdx[j + sub]);
        LDA8(0) LDA8(1) LDA8(2) LDA8(3) LDA8(4) LDA8(5) LDA8(6) LDA8(7)
        ACCP4(va0, va1, va2, va3) ACCP4(va4, va5, va6, va7)
        j += 8;
    }
    if (j + 4 <= end) {
        int s0 = srcIdx[j], s1 = srcIdx[j + 1], s2 = srcIdx[j + 2], s3 = srcIdx[j + 3];
        float4 v0 = unpack4(tab[(size_t)s0 * 8 + sub]);
        float4 v1 = unpack4(tab[(size_t)s1 * 8 + sub]);
        float4 v2 = unpack4(tab[(size_t)s2 * 8 + sub]);
        float4 v3 = unpack4(tab[(size_t)s3 * 8 + sub]);
        ACCP4(v0, v1, v2, v3)
        j += 4;
    }
    for (; j < end; ++j) {
        float4 v = unpack4(tab[(size_t)srcIdx[j] * 8 + sub]);
        acc.x += v.x; acc.y += v.y; acc.z += v.z; acc.w += v.w;
    }
#undef LDA8
#undef LDB8
    float dd = dinv[d];
    float4 b = ((const float4*)bias)[sub];
    short4 pv = pack4(fmaxf(acc.x * dd + b.x, 0.f) * dd,
                      fmaxf(acc.y * dd + b.y, 0.f) * dd,
                      fmaxf(acc.z * dd + b.z, 0.f) * dd,
                      fmaxf(acc.w * dd + b.w, 0.f) * dd);
    nt_store_s4(pv, &outv[(size_t)d * 8 + sub]);
}

// layer 2: out = dinv_d*(self+sum) + b2. g32 = 1 line/edge; g8 = 16B (L2-resident).
__global__ void agg40_kernel(const int* __restrict__ rowbeg,
                             const int* __restrict__ rowend,
                             const int* __restrict__ srcIdx,
                             const float* __restrict__ dinv,
                             const short4* __restrict__ g32v,
                             const short4* __restrict__ g8v,
                             const float* __restrict__ bias,
                             float* __restrict__ out, int n) {
    int t = blockIdx.x * blockDim.x + threadIdx.x;
    int d = t >> 4, sub = t & 15;
    if (d >= n) return;
    int gbase = threadIdx.x & 48;
    bool act = sub < 10;
    const short4* tab = (sub < 8) ? (g32v + sub) : (g8v + (sub - 8));
    size_t stride = (sub < 8) ? 8 : 2;
    float4 acc = make_float4(0.f, 0.f, 0.f, 0.f);
    if (act) acc = unpack4(tab[(size_t)d * stride]);   // self-loop term
    int beg = __builtin_nontemporal_load(&rowbeg[d]);
    int end = __builtin_nontemporal_load(&rowend[d]);
    int j = beg;
#define SH40(Q) int s##Q = __shfl(myIdx, gbase + Q);
#define G40(Q)  float4 v##Q = unpack4(tab[(size_t)s##Q * stride]);
    for (; j + 16 <= end; j += 16) {
        int myIdx = __builtin_nontemporal_load(&srcIdx[j + sub]);
        SH40(0) SH40(1) SH40(2) SH40(3) SH40(4) SH40(5) SH40(6) SH40(7)
        SH40(8) SH40(9) SH40(10) SH40(11) SH40(12) SH40(13) SH40(14) SH40(15)
        if (act) {
            G40(0) G40(1) G40(2) G40(3) G40(4) G40(5) G40(6) G40(7)
            G40(8) G40(9) G40(10) G40(11) G40(12) G40(13) G40(14) G40(15)
            ACCP4(v0, v1, v2, v3) ACCP4(v4, v5, v6, v7)
            ACCP4(v8, v9, v10, v11) ACCP4(v12, v13, v14, v15)
        }
    }
    if (j + 8 <= end) {
        int myIdx = __builtin_nontemporal_load(&srcIdx[j + sub]);  // region slack safe
        SH40(0) SH40(1) SH40(2) SH40(3) SH40(4) SH40(5) SH40(6) SH40(7)
        if (act) {
            G40(0) G40(1) G40(2) G40(3) G40(4) G40(5) G40(6) G40(7)
            ACCP4(v0, v1, v2, v3) ACCP4(v4, v5, v6, v7)
        }
        j += 8;
    }
    if (j + 4 <= end) {
        int s0 = srcIdx[j], s1 = srcIdx[j + 1], s2 = srcIdx[j + 2], s3 = srcIdx[j + 3];
        if (act) {
            float4 v0 = unpack4(tab[(size_t)s0 * stride]);
            float4 v1 = unpack4(tab[(size_t)s1 * stride]);
            float4 v2 = unpack4(tab[(size_t)s2 * stride]);
            float4 v3 = unpack4(tab[(size_t)s3 * stride]);
            ACCP4(v0, v1, v2, v3)
        }
        j += 4;
    }
    for (; j < end; ++j) {
        int s = srcIdx[j];
        if (act) {
            float4 v = unpack4(tab[(size_t)s * stride]);
            acc.x += v.x; acc.y += v.y; acc.z += v.z; acc.w += v.w;
        }
    }
#undef SH40
#undef G40
    if (act) {
        float dd = dinv[d];
        int c0 = 4 * sub;
        float* o = &out[(size_t)d * F_OUT + c0];
        __builtin_nontemporal_store(acc.x * dd + bias[c0], &o[0]);
        if (c0 + 1 < F_OUT) __builtin_nontemporal_store(acc.y * dd + bias[c0 + 1], &o[1]);
        if (c0 + 2 < F_OUT) __builtin_nontemporal_store(acc.z * dd + bias[c0 + 2], &o[2]);
        if (c0 + 3 < F_OUT) __builtin_nontemporal_store(acc.w * dd + bias[c0 + 3], &o[3]);
    }
}

extern "C" void kernel_launch(void* const* d_in, const int* in_sizes, int n_in,
                              void* d_out, int out_size, void* d_ws, size_t ws_size,
                              hipStream_t stream) {
    const float* x  = (const float*)d_in[0];
    const int*   ei = (const int*)d_in[1];
    const float* W1 = (const float*)d_in[2];
    const float* b1 = (const float*)d_in[3];
    const float* W2 = (const float*)d_in[4];
    const float* b2 = (const float*)d_in[5];
    float* out = (float*)d_out;

    const int n = in_sizes[0] / 64;   // 50000
    const int E = in_sizes[1] / 2;    // 800000
    const int* src = ei;
    const int* dst = ei + E;

    const int nb = (n + BSIZE - 1) >> BSHIFT;            // 391 buckets
    const int nblkA = (E + STAGE_CAP - 1) / STAGE_CAP;   // 131
    const int C = (E + nblkA - 1) / nblkA;

    // ---- workspace layout (16B-aligned pieces) ----
    char* p = (char*)d_ws;
    int*   gcur   = (int*)p;   p += (size_t)nb * 16 * 4;        // padded counters
    int*   rowbeg = (int*)p;   p += (size_t)(n + 4) * 4;
    int*   rowend = (int*)p;   p += (size_t)(n + 4) * 4;
    float* dinv   = (float*)p; p += (size_t)n * 4;
    int*   srcIdx = (int*)p;   p += ((size_t)nb * CAP + 16) * 4; // fixed regions, 4.8 MB
    short4* hv0   = (short4*)p; p += (size_t)n * 32 * 2;        // slice 0, 3.2 MB
    short4* hv1   = (short4*)p; p += (size_t)n * 32 * 2;        // slice 1, 3.2 MB
    short4* h1v0  = (short4*)p; p += (size_t)n * 32 * 2;
    short4* h1v1  = (short4*)p; p += (size_t)n * 32 * 2;
    unsigned* bedge = (unsigned*)hv0;        // 4.8 MB region, dead before gemm64
    short4* g32v  = hv0;                     // layer-2 main table, 3.2 MB
    short4* g8v   = hv1;                     // layer-2 tail table, 800 KB

    // ---- CSR build ----
    hipMemsetAsync(gcur, 0, (size_t)nb * 16 * 4, stream);
    bucketA<<<nblkA, 256, 0, stream>>>(src, dst, E, C, nb, gcur, bedge);
    bucketB<<<nb, 256, 0, stream>>>(bedge, gcur, n, rowbeg, rowend, srcIdx, dinv);

    const int gemmBlocks = (n + 63) / 64;
    const int aggS   = (n * 8 + 255) / 256;      // 8 lanes/node slice kernels
    const int agg16  = (n * 16 + 255) / 256;

    // ---- layer 1: slices, sequential so each 3.2MB table is L2-resident ----
    gemm64<<<gemmBlocks, 256, 0, stream>>>(x, W1, dinv, hv0, hv1, n);
    agg64s<<<aggS, 256, 0, stream>>>(rowbeg, rowend, srcIdx, dinv, hv0, b1,      h1v0, n);
    agg64s<<<aggS, 256, 0, stream>>>(rowbeg, rowend, srcIdx, dinv, hv1, b1 + 32, h1v1, n);

    // ---- layer 2: g32/g8 = fp16(h1@W2) ; out = dinv*agg + b2 ----
    gemm37<<<gemmBlocks, 256, 0, stream>>>(h1v0, h1v1, W2, g32v, g8v, n);
    agg40_kernel<<<agg16, 256, 0, stream>>>(rowbeg, rowend, srcIdx, dinv, g32v, g8v, b2, out, n);
}

// Round 14
// 110.631 us; speedup vs baseline: 1.1456x; 1.1456x over previous
//
#include <hip/hip_runtime.h>
#include <hip/hip_fp16.h>

#define F_OUT 37
#define BSHIFT 7
#define BSIZE 128          // nodes per bucket
#define CAP 3072           // edge capacity per bucket region (mean 2048, max ~2300)
#define STAGE_CAP 6144     // max edges staged per bucketA block (24 KB LDS)
#define XS_STRIDE 68       // 64 + 4 pad: breaks bank aliasing, keeps 16B align

// ---------- fp16 pack/unpack helpers ----------
__device__ __forceinline__ short4 pack4(float a, float b, float c, float d) {
    union { __half2 h2[2]; short4 s; } u;
    u.h2[0] = __floats2half2_rn(a, b);
    u.h2[1] = __floats2half2_rn(c, d);
    return u.s;
}
__device__ __forceinline__ float4 unpack4(short4 v) {
    union { short4 s; __half2 h2[2]; } u;
    u.s = v;
    float2 lo = __half22float2(u.h2[0]);
    float2 hi = __half22float2(u.h2[1]);
    return make_float4(lo.x, lo.y, hi.x, hi.y);
}

// ================= bucket-sort CSR build (fixed regions, no scan) =================

__global__ __launch_bounds__(256) void bucketA(const int* __restrict__ src,
                                               const int* __restrict__ dst,
                                               int E, int C, int nb,
                                               int* __restrict__ gcur,
                                               unsigned* __restrict__ bedge) {
    __shared__ unsigned stage[STAGE_CAP];
    __shared__ int lcnt[400];
    __shared__ int lbase[400];
    int t = threadIdx.x;
    int e0 = blockIdx.x * C;
    int cnt = E - e0; if (cnt > C) cnt = C; if (cnt <= 0) return;

    for (int i = t; i < nb; i += 256) lcnt[i] = 0;
    __syncthreads();
    for (int i = t; i < cnt; i += 256) {
        int s = src[e0 + i], d = dst[e0 + i];
        int b = d >> BSHIFT;
        atomicAdd(&lcnt[b], 1);
        stage[i] = ((unsigned)b << 23) | ((unsigned)(d & (BSIZE - 1)) << 16) | (unsigned)s;
    }
    __syncthreads();
    for (int i = t; i < nb; i += 256)
        lbase[i] = lcnt[i] ? atomicAdd(&gcur[i * 16], lcnt[i]) : 0;
    __syncthreads();
    for (int i = t; i < nb; i += 256) lcnt[i] = 0;   // reuse as cursor
    __syncthreads();
    for (int i = t; i < cnt; i += 256) {
        unsigned w = stage[i];
        int b = w >> 23;
        int pos = b * CAP + lbase[b] + atomicAdd(&lcnt[b], 1);
        bedge[pos] = w & 0x7FFFFFu;                  // (dloc<<16)|src
    }
}

__global__ __launch_bounds__(256) void bucketB(const unsigned* __restrict__ bedge,
                                               const int* __restrict__ gcur,
                                               int n,
                                               int* __restrict__ rowbeg,
                                               int* __restrict__ rowend,
                                               int* __restrict__ srcIdx,
                                               float* __restrict__ dinv) {
    __shared__ int hcnt[BSIZE], hoff[BSIZE], hcur[BSIZE], tmp[BSIZE];
    int b = blockIdx.x;
    int t = threadIdx.x;
    int cntb = gcur[b * 16];
    int base = b * CAP;
    const unsigned* ed = bedge + (size_t)base;

    if (t < BSIZE) { hcnt[t] = 0; hcur[t] = 0; }
    __syncthreads();
    for (int i = t; i < cntb; i += 256) atomicAdd(&hcnt[ed[i] >> 16], 1);
    __syncthreads();
    if (t < BSIZE) tmp[t] = hcnt[t];
    __syncthreads();
    for (int o = 1; o < BSIZE; o <<= 1) {
        int a = (t < BSIZE && t >= o) ? tmp[t - o] : 0;
        __syncthreads();
        if (t < BSIZE) tmp[t] += a;
        __syncthreads();
    }
    if (t < BSIZE) hoff[t] = tmp[t] - hcnt[t];
    __syncthreads();
    int node = b * BSIZE + t;
    if (t < BSIZE && node < n) {
        rowbeg[node] = base + hoff[t];
        rowend[node] = base + hoff[t] + hcnt[t];
        dinv[node] = rsqrtf(1.0f + (float)hcnt[t]);   // +1 self-loop
    }
    for (int i = t; i < cntb; i += 256) {
        unsigned w = ed[i];
        int dloc = w >> 16;
        int pos = base + hoff[dloc] + atomicAdd(&hcur[dloc], 1);
        srcIdx[pos] = (int)(w & 0xFFFFu);
    }
}

// ================= dense layers: 64x64 block tile, 4x4 per thread =================

#define MICRO_STEP(XI, ACC)                                                    \
    do {                                                                       \
        ACC[0] += XI.x * w0.x; ACC[1] += XI.x * w0.y;                          \
        ACC[2] += XI.x * w0.z; ACC[3] += XI.x * w0.w;                          \
        ACC[0] += XI.y * w1.x; ACC[1] += XI.y * w1.y;                          \
        ACC[2] += XI.y * w1.z; ACC[3] += XI.y * w1.w;                          \
        ACC[0] += XI.z * w2.x; ACC[1] += XI.z * w2.y;                          \
        ACC[2] += XI.z * w2.z; ACC[3] += XI.z * w2.w;                          \
        ACC[0] += XI.w * w3.x; ACC[1] += XI.w * w3.y;                          \
        ACC[2] += XI.w * w3.z; ACC[3] += XI.w * w3.w;                          \
    } while (0)

// hsv[row][c] (fp16, 16 short4/row) = dinv[row] * sum_k x[row][k]*W[k][c]
__global__ __launch_bounds__(256, 4) void gemm64(const float* __restrict__ x,
                                                 const float* __restrict__ W,
                                                 const float* __restrict__ dinv,
                                                 short4* __restrict__ hsv, int n) {
    __shared__ float Xs[64 * XS_STRIDE];
    __shared__ float Ws[64 * 64];
    int t = threadIdx.x;
    const float4* W4 = (const float4*)W;
#pragma unroll
    for (int i = 0; i < 4; ++i)
        ((float4*)Ws)[t + i * 256] = W4[t + i * 256];
    int row0 = blockIdx.x * 64;
#pragma unroll
    for (int i = 0; i < 4; ++i) {
        int idx = i * 256 + t;            // 0..1023
        int r = idx >> 4, k4 = idx & 15;
        int grow = row0 + r;
        float4 v = (grow < n) ? ((const float4*)x)[(size_t)grow * 16 + k4]
                              : make_float4(0.f, 0.f, 0.f, 0.f);
        *(float4*)&Xs[r * XS_STRIDE + k4 * 4] = v;
    }
    __syncthreads();

    int tc = t & 15, tr = t >> 4;
    float a0[4] = {0.f, 0.f, 0.f, 0.f};
    float a1[4] = {0.f, 0.f, 0.f, 0.f};
    float a2[4] = {0.f, 0.f, 0.f, 0.f};
    float a3[4] = {0.f, 0.f, 0.f, 0.f};

#pragma unroll 2
    for (int k = 0; k < 64; k += 4) {
        float4 w0 = *(const float4*)&Ws[(k + 0) * 64 + 4 * tc];
        float4 w1 = *(const float4*)&Ws[(k + 1) * 64 + 4 * tc];
        float4 w2 = *(const float4*)&Ws[(k + 2) * 64 + 4 * tc];
        float4 w3 = *(const float4*)&Ws[(k + 3) * 64 + 4 * tc];
        float4 x0 = *(const float4*)&Xs[(4 * tr + 0) * XS_STRIDE + k];
        float4 x1 = *(const float4*)&Xs[(4 * tr + 1) * XS_STRIDE + k];
        float4 x2 = *(const float4*)&Xs[(4 * tr + 2) * XS_STRIDE + k];
        float4 x3 = *(const float4*)&Xs[(4 * tr + 3) * XS_STRIDE + k];
        MICRO_STEP(x0, a0);
        MICRO_STEP(x1, a1);
        MICRO_STEP(x2, a2);
        MICRO_STEP(x3, a3);
    }

#define STORE64(ACC, R)                                                        \
    do {                                                                       \
        int row = row0 + 4 * tr + (R);                                         \
        if (row < n) {                                                         \
            float dd = dinv[row];                                              \
            hsv[(size_t)row * 16 + tc] =                                       \
                pack4(ACC[0] * dd, ACC[1] * dd, ACC[2] * dd, ACC[3] * dd);     \
        }                                                                      \
    } while (0)
    STORE64(a0, 0); STORE64(a1, 1); STORE64(a2, 2); STORE64(a3, 3);
#undef STORE64
}

// layer-2 GEMM: g32[row][0..31] (one 64B line) + g8[row][32..39] (16B row, 800KB)
__global__ __launch_bounds__(256, 4) void gemm37(const short4* __restrict__ h1v,
                                                 const float* __restrict__ W,
                                                 short4* __restrict__ g32v,
                                                 short4* __restrict__ g8v, int n) {
    __shared__ float Xs[64 * XS_STRIDE];
    __shared__ float Ws[64 * 64];       // zero-padded cols 37..63
    int t = threadIdx.x;
    for (int i = t; i < 64 * 64; i += 256) {
        int k = i >> 6, c = i & 63;
        Ws[i] = (c < F_OUT) ? W[k * F_OUT + c] : 0.f;
    }
    int row0 = blockIdx.x * 64;
#pragma unroll
    for (int i = 0; i < 4; ++i) {
        int idx = i * 256 + t;
        int r = idx >> 4, k4 = idx & 15;
        int grow = row0 + r;
        float4 v = (grow < n) ? unpack4(h1v[(size_t)grow * 16 + k4])
                              : make_float4(0.f, 0.f, 0.f, 0.f);
        *(float4*)&Xs[r * XS_STRIDE + k4 * 4] = v;
    }
    __syncthreads();

    int tc = t & 15, tr = t >> 4;
    float a0[4] = {0.f, 0.f, 0.f, 0.f};
    float a1[4] = {0.f, 0.f, 0.f, 0.f};
    float a2[4] = {0.f, 0.f, 0.f, 0.f};
    float a3[4] = {0.f, 0.f, 0.f, 0.f};

#pragma unroll 2
    for (int k = 0; k < 64; k += 4) {
        float4 w0 = *(const float4*)&Ws[(k + 0) * 64 + 4 * tc];
        float4 w1 = *(const float4*)&Ws[(k + 1) * 64 + 4 * tc];
        float4 w2 = *(const float4*)&Ws[(k + 2) * 64 + 4 * tc];
        float4 w3 = *(const float4*)&Ws[(k + 3) * 64 + 4 * tc];
        float4 x0 = *(const float4*)&Xs[(4 * tr + 0) * XS_STRIDE + k];
        float4 x1 = *(const float4*)&Xs[(4 * tr + 1) * XS_STRIDE + k];
        float4 x2 = *(const float4*)&Xs[(4 * tr + 2) * XS_STRIDE + k];
        float4 x3 = *(const float4*)&Xs[(4 * tr + 3) * XS_STRIDE + k];
        MICRO_STEP(x0, a0);
        MICRO_STEP(x1, a1);
        MICRO_STEP(x2, a2);
        MICRO_STEP(x3, a3);
    }

    if (tc < 10) {   // cols 0..39 live
#define STORE37(ACC, R)                                                        \
        do {                                                                   \
            int row = row0 + 4 * tr + (R);                                     \
            if (row < n) {                                                     \
                short4 pv = pack4(ACC[0], ACC[1], ACC[2], ACC[3]);             \
                if (tc < 8) g32v[(size_t)row * 8 + tc] = pv;                   \
                else        g8v[(size_t)row * 2 + (tc - 8)] = pv;              \
            }                                                                  \
        } while (0)
        STORE37(a0, 0); STORE37(a1, 1); STORE37(a2, 2); STORE37(a3, 3);
#undef STORE37
    }
}

// ================= gather aggregation (fp16 tables, fp32 accum) =================

#define ACCP4(A, B, C, D)                                                      \
    acc.x += (A.x + B.x) + (C.x + D.x);                                        \
    acc.y += (A.y + B.y) + (C.y + D.y);                                        \
    acc.z += (A.z + B.z) + (C.z + D.z);                                        \
    acc.w += (A.w + B.w) + (C.w + D.w);

// layer 1: h1 = fp16(dinv * relu(dinv*(self+sum) + b1)); 16 lanes/node, 8B/lane
__global__ void agg64_kernel(const int* __restrict__ rowbeg,
                             const int* __restrict__ rowend,
                             const int* __restrict__ srcIdx,
                             const float* __restrict__ dinv,
                             const short4* __restrict__ hsv,
                             const float* __restrict__ bias,
                             short4* __restrict__ outv, int n) {
    int t = blockIdx.x * blockDim.x + threadIdx.x;
    int d = t >> 4, sub = t & 15;
    if (d >= n) return;
    int gbase = threadIdx.x & 48;
    float4 acc = unpack4(hsv[(size_t)d * 16 + sub]);   // self-loop term
    int beg = rowbeg[d], end = rowend[d];
    int j = beg;
#define LD64(Q) float4 v##Q = unpack4(hsv[(size_t)__shfl(myIdx, gbase + Q) * 16 + sub]);
    for (; j + 16 <= end; j += 16) {
        int myIdx = srcIdx[j + sub];
        LD64(0) LD64(1) LD64(2) LD64(3) LD64(4) LD64(5) LD64(6) LD64(7)
        LD64(8) LD64(9) LD64(10) LD64(11) LD64(12) LD64(13) LD64(14) LD64(15)
        ACCP4(v0, v1, v2, v3) ACCP4(v4, v5, v6, v7)
        ACCP4(v8, v9, v10, v11) ACCP4(v12, v13, v14, v15)
    }
    if (j + 8 <= end) {
        int myIdx = srcIdx[j + sub];   // lanes sub>=8 read region slack (safe)
        LD64(0) LD64(1) LD64(2) LD64(3) LD64(4) LD64(5) LD64(6) LD64(7)
        ACCP4(v0, v1, v2, v3) ACCP4(v4, v5, v6, v7)
        j += 8;
    }
    if (j + 4 <= end) {
        int s0 = srcIdx[j], s1 = srcIdx[j + 1], s2 = srcIdx[j + 2], s3 = srcIdx[j + 3];
        float4 v0 = unpack4(hsv[(size_t)s0 * 16 + sub]);
        float4 v1 = unpack4(hsv[(size_t)s1 * 16 + sub]);
        float4 v2 = unpack4(hsv[(size_t)s2 * 16 + sub]);
        float4 v3 = unpack4(hsv[(size_t)s3 * 16 + sub]);
        ACCP4(v0, v1, v2, v3)
        j += 4;
    }
    for (; j < end; ++j) {
        float4 v = unpack4(hsv[(size_t)srcIdx[j] * 16 + sub]);
        acc.x += v.x; acc.y += v.y; acc.z += v.z; acc.w += v.w;
    }
#undef LD64
    float dd = dinv[d];
    float4 b = ((const float4*)bias)[sub];
    outv[(size_t)d * 16 + sub] =
        pack4(fmaxf(acc.x * dd + b.x, 0.f) * dd,
              fmaxf(acc.y * dd + b.y, 0.f) * dd,
              fmaxf(acc.z * dd + b.z, 0.f) * dd,
              fmaxf(acc.w * dd + b.w, 0.f) * dd);
}

// layer 2: out = dinv_d*(self+sum) + b2. Gather = 1 line (g32) + 16B row (g8).
__global__ void agg40_kernel(const int* __restrict__ rowbeg,
                             const int* __restrict__ rowend,
                             const int* __restrict__ srcIdx,
                             const float* __restrict__ dinv,
                             const short4* __restrict__ g32v,
                             const short4* __restrict__ g8v,
                             const float* __restrict__ bias,
                             float* __restrict__ out, int n) {
    int t = blockIdx.x * blockDim.x + threadIdx.x;
    int d = t >> 4, sub = t & 15;
    if (d >= n) return;
    int gbase = threadIdx.x & 48;
    bool act = sub < 10;
    const short4* tab = (sub < 8) ? (g32v + sub) : (g8v + (sub - 8));
    size_t stride = (sub < 8) ? 8 : 2;
    float4 acc = make_float4(0.f, 0.f, 0.f, 0.f);
    if (act) acc = unpack4(tab[(size_t)d * stride]);   // self-loop term
    int beg = rowbeg[d], end = rowend[d];
    int j = beg;
#define SH40(Q) int s##Q = __shfl(myIdx, gbase + Q);
#define G40(Q)  float4 v##Q = unpack4(tab[(size_t)s##Q * stride]);
    for (; j + 16 <= end; j += 16) {
        int myIdx = srcIdx[j + sub];
        SH40(0) SH40(1) SH40(2) SH40(3) SH40(4) SH40(5) SH40(6) SH40(7)
        SH40(8) SH40(9) SH40(10) SH40(11) SH40(12) SH40(13) SH40(14) SH40(15)
        if (act) {
            G40(0) G40(1) G40(2) G40(3) G40(4) G40(5) G40(6) G40(7)
            G40(8) G40(9) G40(10) G40(11) G40(12) G40(13) G40(14) G40(15)
            ACCP4(v0, v1, v2, v3) ACCP4(v4, v5, v6, v7)
            ACCP4(v8, v9, v10, v11) ACCP4(v12, v13, v14, v15)
        }
    }
    if (j + 8 <= end) {
        int myIdx = srcIdx[j + sub];   // region slack safe
        SH40(0) SH40(1) SH40(2) SH40(3) SH40(4) SH40(5) SH40(6) SH40(7)
        if (act) {
            G40(0) G40(1) G40(2) G40(3) G40(4) G40(5) G40(6) G40(7)
            ACCP4(v0, v1, v2, v3) ACCP4(v4, v5, v6, v7)
        }
        j += 8;
    }
    if (j + 4 <= end) {
        int s0 = srcIdx[j], s1 = srcIdx[j + 1], s2 = srcIdx[j + 2], s3 = srcIdx[j + 3];
        if (act) {
            float4 v0 = unpack4(tab[(size_t)s0 * stride]);
            float4 v1 = unpack4(tab[(size_t)s1 * stride]);
            float4 v2 = unpack4(tab[(size_t)s2 * stride]);
            float4 v3 = unpack4(tab[(size_t)s3 * stride]);
            ACCP4(v0, v1, v2, v3)
        }
        j += 4;
    }
    for (; j < end; ++j) {
        int s = srcIdx[j];
        if (act) {
            float4 v = unpack4(tab[(size_t)s * stride]);
            acc.x += v.x; acc.y += v.y; acc.z += v.z; acc.w += v.w;
        }
    }
#undef SH40
#undef G40
    if (act) {
        float dd = dinv[d];
        int c0 = 4 * sub;
        float* o = &out[(size_t)d * F_OUT + c0];
        o[0] = acc.x * dd + bias[c0];
        if (c0 + 1 < F_OUT) o[1] = acc.y * dd + bias[c0 + 1];
        if (c0 + 2 < F_OUT) o[2] = acc.z * dd + bias[c0 + 2];
        if (c0 + 3 < F_OUT) o[3] = acc.w * dd + bias[c0 + 3];
    }
}

extern "C" void kernel_launch(void* const* d_in, const int* in_sizes, int n_in,
                              void* d_out, int out_size, void* d_ws, size_t ws_size,
                              hipStream_t stream) {
    const float* x  = (const float*)d_in[0];
    const int*   ei = (const int*)d_in[1];
    const float* W1 = (const float*)d_in[2];
    const float* b1 = (const float*)d_in[3];
    const float* W2 = (const float*)d_in[4];
    const float* b2 = (const float*)d_in[5];
    float* out = (float*)d_out;

    const int n = in_sizes[0] / 64;   // 50000
    const int E = in_sizes[1] / 2;    // 800000
    const int* src = ei;
    const int* dst = ei + E;

    const int nb = (n + BSIZE - 1) >> BSHIFT;            // 391 buckets
    const int nblkA = (E + STAGE_CAP - 1) / STAGE_CAP;   // 131
    const int C = (E + nblkA - 1) / nblkA;

    // ---- workspace layout (16B-aligned pieces) ----
    char* p = (char*)d_ws;
    int*   gcur   = (int*)p;   p += (size_t)nb * 16 * 4;        // padded counters
    int*   rowbeg = (int*)p;   p += (size_t)(n + 4) * 4;
    int*   rowend = (int*)p;   p += (size_t)(n + 4) * 4;
    float* dinv   = (float*)p; p += (size_t)n * 4;
    int*   srcIdx = (int*)p;   p += ((size_t)nb * CAP + 16) * 4; // fixed regions, 4.8 MB
    short4* hsv   = (short4*)p; p += (size_t)n * 64 * 2;        // fp16 table, 6.4 MB
    short4* h1v   = (short4*)p; p += (size_t)n * 64 * 2;        // fp16 table, 6.4 MB
    unsigned* bedge = (unsigned*)hsv;        // 4.8 MB region, dead before gemm64
    short4* g32v  = hsv;                     // layer-2 main table, 3.2 MB
    short4* g8v   = hsv + (size_t)n * 8;     // layer-2 tail table, 800 KB

    // ---- CSR build (memset + 2 kernels; no scan, fixed regions) ----
    hipMemsetAsync(gcur, 0, (size_t)nb * 16 * 4, stream);
    bucketA<<<nblkA, 256, 0, stream>>>(src, dst, E, C, nb, gcur, bedge);
    bucketB<<<nb, 256, 0, stream>>>(bedge, gcur, n, rowbeg, rowend, srcIdx, dinv);

    const int gemmBlocks = (n + 63) / 64;
    const int aggBlocks  = (n * 16 + 255) / 256;

    // ---- layer 1: hs = fp16((x@W1)*dinv) ; h1 = fp16(dinv*relu(dinv*agg + b1)) ----
    gemm64<<<gemmBlocks, 256, 0, stream>>>(x, W1, dinv, hsv, n);
    agg64_kernel<<<aggBlocks, 256, 0, stream>>>(rowbeg, rowend, srcIdx, dinv, hsv, b1, h1v, n);

    // ---- layer 2: g32/g8 = fp16(h1@W2) ; out = dinv*agg + b2 ----
    gemm37<<<gemmBlocks, 256, 0, stream>>>(h1v, W2, g32v, g8v, n);
    agg40_kernel<<<aggBlocks, 256, 0, stream>>>(rowbeg, rowend, srcIdx, dinv, g32v, g8v, b2, out, n);
}